// Round 8
// baseline (297.871 us; speedup 1.0000x reference)
//
#include <hip/hip_runtime.h>

// Problem constants (from reference)
constexpr int B    = 1024;
constexpr int L    = 50;
constexpr int S    = 256;
constexpr int H    = 4;
constexpr int E    = 64;
constexpr int HID  = 64;
constexpr int SUPP = 10000;

// Broadcast lane l's value to all lanes of the wave (l must be wave-uniform;
// compiles to v_readlane -> SGPR, usable as the scalar operand of v_fma).
__device__ __forceinline__ float lanebc(float v, int l) {
    return __int_as_float(__builtin_amdgcn_readlane(__float_as_int(v), l));
}

// 64-long broadcast dot, 2 chains (cold paths only).
__device__ __forceinline__ float bcdot64(float v, const float* w) {
    float a0 = 0.0f, a1 = 0.0f;
#pragma unroll
    for (int i = 0; i < E; i += 2) {
        a0 += lanebc(v, i)     * w[i];
        a1 += lanebc(v, i + 1) * w[i + 1];
    }
    return a0 + a1;
}

// ---------------------------------------------------------------------------
// Kernel 1: fused pre-work.
//   blockIdx.y in {0,1}: user_fea_encode(call=y) + per-head q projection
//     (wave == head); fea never touches global memory.
//   blockIdx.y == 2:     K_supp[h][j][:] = tgt_user_emb[supp_users[j]] @ Wk[h]
// Reference quirks preserved: src_item_emb for BOTH encode calls; encoder
// softmax has no max-subtract, padded rows contribute exp(0)=1; denom+1e-12.
// Staging is SYNCHRONOUS load->ds_write (R7's async global_load_lds bypassed
// L1 and raised HBM FETCH 8.8->15 MB -- reverted).
// ---------------------------------------------------------------------------
__global__ __launch_bounds__(256) void pre_kernel(
    const int* __restrict__ x,            // (B,2)  [:,0]=user_id
    const int* __restrict__ src_his,      // (B,L)
    const int* __restrict__ src_hl,       // (B,)
    const int* __restrict__ tgt_his,      // (B,L)
    const int* __restrict__ tgt_hl,       // (B,)
    const float* __restrict__ item_emb,   // src_item_emb -- always src!
    const float* __restrict__ src_user_emb,
    const float* __restrict__ tgt_user_emb,
    const int* __restrict__ supp_users,   // (SUPP,)
    const float* __restrict__ W_att_w,    // (E,E)
    const float* __restrict__ W_att_b,    // (E,)
    const float* __restrict__ W_agg_w,    // (E,E)
    const float* __restrict__ Wq,         // (H,E,E)
    const float* __restrict__ Wk,         // (H,E,E)
    float* __restrict__ qout,             // (2,H,B,E)
    float* __restrict__ K_supp)           // (H,SUPP,E)
{
    const int tid  = threadIdx.x;
    const int lane = tid & 63;
    const int wave = tid >> 6;

    if (blockIdx.y == 2) {
        // ---------------- ksupp plane: 4 j's at once ----------------
        const int h = wave;   // wave == head
        float wcol[E];
#pragma unroll
        for (int i = 0; i < E; i++) wcol[i] = Wk[h * E * E + i * E + lane];

        const int base = blockIdx.x * 4;          // gridDim.x = 1024
#pragma unroll
        for (int m = 0; m < 3; m++) {
            const int j0 = base + m * 4096;
            if (j0 >= SUPP) break;                // groups 4-aligned; SUPP%4==0
            const int u0 = supp_users[j0];
            const int u1 = supp_users[j0 + 1];
            const int u2 = supp_users[j0 + 2];
            const int u3 = supp_users[j0 + 3];
            const float e0 = tgt_user_emb[(size_t)u0 * E + lane];
            const float e1 = tgt_user_emb[(size_t)u1 * E + lane];
            const float e2 = tgt_user_emb[(size_t)u2 * E + lane];
            const float e3 = tgt_user_emb[(size_t)u3 * E + lane];
            float a0 = 0.0f, a1 = 0.0f, a2 = 0.0f, a3 = 0.0f;
#pragma unroll
            for (int i = 0; i < E; i++) {
                a0 += lanebc(e0, i) * wcol[i];
                a1 += lanebc(e1, i) * wcol[i];
                a2 += lanebc(e2, i) * wcol[i];
                a3 += lanebc(e3, i) * wcol[i];
            }
            float* dst = K_supp + ((size_t)h * SUPP + j0) * E + lane;
            dst[0]     = a0;
            dst[E]     = a1;
            dst[2 * E] = a2;
            dst[3 * E] = a3;
        }
        return;
    }

    // ---------------- encode + q plane ----------------
    __shared__ float sHist[L * E];
    __shared__ float sAtt[L];
    __shared__ float sPart[4][E];
    __shared__ float sOut[E];

    const int b    = blockIdx.x;
    const int call = blockIdx.y;

    const int* his = call ? tgt_his : src_his;
    const int* hl  = call ? tgt_hl  : src_hl;
    const float* user_table = call ? tgt_user_emb : src_user_emb;

    float wcol[E];
#pragma unroll
    for (int i = 0; i < E; i++) wcol[i] = W_att_w[i * E + lane];

    const int uid    = x[2 * b];
    const float uv   = user_table[(size_t)uid * E + lane];
    const float bias = W_att_b[lane];
    const int hlen   = hl[b];

    // phase 1a: stage ALL history rows (masked) to LDS; synchronous loads so
    // item_emb reuse is L1-served; all 13 loads issued before any use.
#pragma unroll
    for (int i = 0; i < 13; i++) {
        const int l = wave + 4 * i;
        if (l < L) {
            const int it = his[b * L + l];
            sHist[l * E + lane] = (l < hlen) ? item_emb[(size_t)it * E + lane] : 0.0f;
        }
    }
    __syncthreads();

    // phase 1b: 4 rows at a time -- 4 independent readlane+fmac chains
    // sharing wcol[i]; each fmac's readlane issued 8 cyc earlier (no hazard).
#pragma unroll
    for (int g = 0; g < 3; g++) {
        const int l0 = wave + 16 * g;
        const int l1 = l0 + 4, l2 = l0 + 8, l3 = l0 + 12;
        const float h0 = sHist[l0 * E + lane];
        const float h1 = sHist[l1 * E + lane];
        const float h2 = sHist[l2 * E + lane];
        const float h3 = sHist[l3 * E + lane];
        float a0 = bias, a1 = bias, a2 = bias, a3 = bias;
#pragma unroll
        for (int i = 0; i < E; i++) {
            a0 += lanebc(h0, i) * wcol[i];
            a1 += lanebc(h1, i) * wcol[i];
            a2 += lanebc(h2, i) * wcol[i];
            a3 += lanebc(h3, i) * wcol[i];
        }
        float p0 = tanhf(a0) * uv, p1 = tanhf(a1) * uv;
        float p2 = tanhf(a2) * uv, p3 = tanhf(a3) * uv;
        float s0 = h0, s1 = h1, s2 = h2, s3 = h3;
#pragma unroll
        for (int off = 32; off; off >>= 1) {
            p0 += __shfl_xor(p0, off); s0 += __shfl_xor(s0, off);
            p1 += __shfl_xor(p1, off); s1 += __shfl_xor(s1, off);
            p2 += __shfl_xor(p2, off); s2 += __shfl_xor(s2, off);
            p3 += __shfl_xor(p3, off); s3 += __shfl_xor(s3, off);
        }
        if (lane == 0) {
            sAtt[l0] = (s0 == 0.0f) ? 0.0f : p0;
            sAtt[l1] = (s1 == 0.0f) ? 0.0f : p1;
            sAtt[l2] = (s2 == 0.0f) ? 0.0f : p2;
            sAtt[l3] = (s3 == 0.0f) ? 0.0f : p3;
        }
    }
    {   // leftover row l = wave + 48 (waves 0,1 only)
        const int l = wave + 48;
        if (l < L) {
            const float hv = sHist[l * E + lane];
            const float a = bias + bcdot64(hv, wcol);
            float part = tanhf(a) * uv;
            float hsum = hv;
#pragma unroll
            for (int off = 32; off; off >>= 1) {
                part += __shfl_xor(part, off);
                hsum += __shfl_xor(hsum, off);
            }
            if (lane == 0) sAtt[l] = (hsum == 0.0f) ? 0.0f : part;
        }
    }
    __syncthreads();

    // softmax (no max-subtract; padded rows contribute exp(0)=1)
    if (wave == 0) {
        float v = (lane < L) ? expf(sAtt[lane]) : 0.0f;
        float s = v;
#pragma unroll
        for (int off = 32; off; off >>= 1) s += __shfl_xor(s, off);
        const float denom = s + 1e-12f;
        if (lane < L) sAtt[lane] = v / denom;
    }
    __syncthreads();

    // ctx partials across waves (2 accumulators)
    {
        float c0 = 0.0f, c1 = 0.0f;
        for (int l = wave; l < L; l += 8) c0 += sAtt[l] * sHist[l * E + lane];
        for (int l = wave + 4; l < L; l += 8) c1 += sAtt[l] * sHist[l * E + lane];
        sPart[wave][lane] = c0 + c1;
    }
    __syncthreads();
    if (tid < E) sOut[tid] = sPart[0][tid] + sPart[1][tid] + sPart[2][tid] + sPart[3][tid];
    __syncthreads();

    // agg: fea = ctx @ W_agg, i-range split across waves (2 accumulators)
    {
        float g0 = 0.0f, g1 = 0.0f;
#pragma unroll
        for (int k = 0; k < 16; k += 2) {
            const int i = wave * 16 + k;
            g0 += sOut[i]     * W_agg_w[i * E + lane];
            g1 += sOut[i + 1] * W_agg_w[(i + 1) * E + lane];
        }
        sPart[wave][lane] = g0 + g1;
    }
    __syncthreads();

    // fea[lane] then q projection (wave == head), 2 accumulators
    const float fval = sPart[0][lane] + sPart[1][lane] + sPart[2][lane] + sPart[3][lane];
    const float* Wqh = Wq + wave * E * E;
    float q0 = 0.0f, q1 = 0.0f;
#pragma unroll
    for (int i = 0; i < E; i += 2) {
        q0 += lanebc(fval, i)     * Wqh[i * E + lane];
        q1 += lanebc(fval, i + 1) * Wqh[(i + 1) * E + lane];
    }
    qout[(((call * H) + wave) * B + b) * E + lane] = q0 + q1;
}

// ---------------------------------------------------------------------------
// Kernel 2: attention per (b,h,call), flat grid with h = bid&3 so that with
// round-robin block->XCD dispatch (bid%8) each XCD serves ONE head whose
// K_supp slice (2.56 MB) fits its 4 MB L2.  K tile lives in REGISTERS:
// lane = (rsub = lane>>4, u = lane&15); wave w owns rows [w*64,(w+1)*64);
// kreg[i] = row (s0+4i+rsub), unit u.  Logits via in-lane partial dot +
// 4-step shuffle reduce in 16-lane subgroups.  softmax = jax.nn.softmax
// (max-subtracted).  ctx is pure-VALU FMA over the register tile; ctx uses k
// itself (reference quirk); g = ctx @ Wv[h].
// ---------------------------------------------------------------------------
__global__ __launch_bounds__(256) void attn_kernel(
    const int* __restrict__ sample_idx,  // (2,H,B,S)
    const float* __restrict__ K_supp,    // (H,SUPP,E)
    const float* __restrict__ qarr,      // (2,H,B,E)
    const float* __restrict__ Wv,        // (H,E,E)
    float* __restrict__ gout)            // (2,B,H*E)
{
    __shared__ float sRed[8];
    __shared__ float sCtx[4][E];
    __shared__ float sC[E];
    __shared__ float sG[4][E];

    const int bid  = blockIdx.x;
    const int h    = bid & 3;          // low bits -> XCD-locality for K_supp
    const int call = (bid >> 2) & 1;
    const int b    = bid >> 3;
    const int tid  = threadIdx.x;
    const int lane = tid & 63;
    const int wave = tid >> 6;
    const int u    = lane & 15;
    const int rsub = lane >> 4;
    const int s0   = wave * 64;

    const int* idx = sample_idx + (((call * H) + h) * B + b) * S;
    const float* Kh = K_supp + (size_t)h * SUPP * E;
    const float4 qu = *(const float4*)(qarr + ((size_t)(((call * H) + h) * B + b)) * E + 4 * u);

    // ---- gather into registers + logits ----
    float4 kreg[16];
    float mylogit = 0.0f;
#pragma unroll
    for (int i = 0; i < 16; i++) {
        const int j = idx[s0 + 4 * i + rsub];
        kreg[i] = *(const float4*)(Kh + (size_t)j * E + 4 * u);
        float part = kreg[i].x * qu.x + kreg[i].y * qu.y
                   + kreg[i].z * qu.z + kreg[i].w * qu.w;
#pragma unroll
        for (int off = 1; off < 16; off <<= 1) part += __shfl_xor(part, off);
        mylogit = (u == i) ? part : mylogit;   // lane holds row s0 + 4u + rsub
    }

    // ---- block softmax over 256 logits (permutation-invariant) ----
    float m = mylogit;
#pragma unroll
    for (int off = 32; off; off >>= 1) m = fmaxf(m, __shfl_xor(m, off));
    if (lane == 0) sRed[wave] = m;
    __syncthreads();
    const float mx = fmaxf(fmaxf(sRed[0], sRed[1]), fmaxf(sRed[2], sRed[3]));
    const float ex = expf(mylogit - mx);
    float sm = ex;
#pragma unroll
    for (int off = 32; off; off >>= 1) sm += __shfl_xor(sm, off);
    if (lane == 0) sRed[4 + wave] = sm;
    __syncthreads();
    const float denom = sRed[4] + sRed[5] + sRed[6] + sRed[7];
    const float pval = ex / denom;   // weight of row s0 + 4u + rsub

    // ---- ctx: pure-VALU FMA over register tile ----
    float4 cacc = make_float4(0.0f, 0.0f, 0.0f, 0.0f);
#pragma unroll
    for (int i = 0; i < 16; i++) {
        const float p = __shfl(pval, (lane & 48) + i);
        cacc.x += p * kreg[i].x;
        cacc.y += p * kreg[i].y;
        cacc.z += p * kreg[i].z;
        cacc.w += p * kreg[i].w;
    }
#pragma unroll
    for (int off = 16; off <= 32; off <<= 1) {
        cacc.x += __shfl_xor(cacc.x, off);
        cacc.y += __shfl_xor(cacc.y, off);
        cacc.z += __shfl_xor(cacc.z, off);
        cacc.w += __shfl_xor(cacc.w, off);
    }
    if (lane < 16) *(float4*)(&sCtx[wave][u * 4]) = cacc;
    __syncthreads();
    if (wave == 0) {
        sC[lane] = sCtx[0][lane] + sCtx[1][lane] + sCtx[2][lane] + sCtx[3][lane];
    }
    __syncthreads();

    // ---- g = ctx @ Wv[h], c-range split across waves (2 accumulators) ----
    const float* Wvh = Wv + h * E * E;
    float g0 = 0.0f, g1 = 0.0f;
#pragma unroll
    for (int k = 0; k < 16; k += 2) {
        const int c = wave * 16 + k;
        g0 += sC[c]     * Wvh[c * E + lane];
        g1 += sC[c + 1] * Wvh[(c + 1) * E + lane];
    }
    sG[wave][lane] = g0 + g1;
    __syncthreads();
    if (wave == 0) {
        gout[((size_t)(call * B) + b) * (H * E) + h * E + lane] =
            sG[0][lane] + sG[1][lane] + sG[2][lane] + sG[3][lane];
    }
}

// ---------------------------------------------------------------------------
// Kernel 3: W_out projection + final MLP + all four outputs.
// out layout: [output(B) | x3(B) | out_emb_s(B*E) | x2(B*E)]
// ---------------------------------------------------------------------------
__global__ __launch_bounds__(256) void final_kernel(
    const int* __restrict__ x,             // (B,2) [:,1]=item_id
    const float* __restrict__ tgt_item_emb,
    const float* __restrict__ gsrc,        // (B, H*E) -> user_emb path
    const float* __restrict__ gtgt,        // (B, H*E) -> hybrid path
    const float* __restrict__ W_out,       // (H*E, E)
    const float* __restrict__ l1_w,        // (2E, HID)
    const float* __restrict__ l1_b,        // (HID,)
    const float* __restrict__ l2_w,        // (HID, E)
    const float* __restrict__ l2_b,        // (E,)
    const float* __restrict__ l3_w,        // (E,1)
    const float* __restrict__ l3_b,        // (1,)
    float* __restrict__ out)
{
    __shared__ float sPart[4][E];
    __shared__ float sHyb[E];
    __shared__ float sItem[E];
    __shared__ float sX1[HID];

    const int b    = blockIdx.x;
    const int tid  = threadIdx.x;
    const int lane = tid & 63;
    const int wave = tid >> 6;

    if (tid < E) {
        const int item = x[2 * b + 1];
        sItem[tid] = tgt_item_emb[(size_t)item * E + tid];
    }

    // W_out projection: waves 0,1 -> gsrc; 2,3 -> gtgt; 4 accumulators each
    const float* grow = (wave < 2) ? (gsrc + (size_t)b * (H * E))
                                   : (gtgt + (size_t)b * (H * E));
    const int i0 = (wave & 1) * 128;
    float a0 = 0.0f, a1 = 0.0f, a2 = 0.0f, a3 = 0.0f;
    for (int i = i0; i < i0 + 128; i += 4) {
        a0 += grow[i]     * W_out[i * E + lane];
        a1 += grow[i + 1] * W_out[(i + 1) * E + lane];
        a2 += grow[i + 2] * W_out[(i + 2) * E + lane];
        a3 += grow[i + 3] * W_out[(i + 3) * E + lane];
    }
    sPart[wave][lane] = (a0 + a1) + (a2 + a3);
    __syncthreads();

    if (wave == 0) {
        const float ue = sPart[0][lane] + sPart[1][lane];
        const float prod = ue * sItem[lane];
        out[2 * B + b * E + lane] = prod;  // out_emb_s
        float s = prod;
#pragma unroll
        for (int off = 32; off; off >>= 1) s += __shfl_xor(s, off);
        if (lane == 0) out[b] = s;         // output
    }
    if (wave == 1) {
        sHyb[lane] = sPart[2][lane] + sPart[3][lane];
    }
    __syncthreads();

    // l1: 128-deep sum split across 4 waves, 4 accumulators
    {
        float b0 = 0.0f, b1 = 0.0f, b2 = 0.0f, b3 = 0.0f;
#pragma unroll
        for (int k = 0; k < 32; k += 4) {
            const int i = wave * 32 + k;
            const float v0 = (i < 64)     ? sHyb[i]          : sItem[i - 64];
            const float v1 = (i + 1 < 64) ? sHyb[i + 1]      : sItem[i + 1 - 64];
            const float v2 = (i + 2 < 64) ? sHyb[i + 2]      : sItem[i + 2 - 64];
            const float v3 = (i + 3 < 64) ? sHyb[i + 3]      : sItem[i + 3 - 64];
            b0 += v0 * l1_w[i * HID + lane];
            b1 += v1 * l1_w[(i + 1) * HID + lane];
            b2 += v2 * l1_w[(i + 2) * HID + lane];
            b3 += v3 * l1_w[(i + 3) * HID + lane];
        }
        sPart[wave][lane] = (b0 + b1) + (b2 + b3);
    }
    __syncthreads();

    if (wave == 0) {
        const float a = l1_b[lane] + sPart[0][lane] + sPart[1][lane]
                      + sPart[2][lane] + sPart[3][lane];
        sX1[lane] = tanhf(a);
    }
    __syncthreads();

    // l2: 64-deep sum split across 4 waves (16 each), 4 accumulators
    {
        float c0 = 0.0f, c1 = 0.0f, c2 = 0.0f, c3 = 0.0f;
#pragma unroll
        for (int k = 0; k < 16; k += 4) {
            const int i = wave * 16 + k;
            c0 += sX1[i]     * l2_w[i * E + lane];
            c1 += sX1[i + 1] * l2_w[(i + 1) * E + lane];
            c2 += sX1[i + 2] * l2_w[(i + 2) * E + lane];
            c3 += sX1[i + 3] * l2_w[(i + 3) * E + lane];
        }
        sPart[wave][lane] = (c0 + c1) + (c2 + c3);
    }
    __syncthreads();

    if (wave == 0) {
        const float a = l2_b[lane] + sPart[0][lane] + sPart[1][lane]
                      + sPart[2][lane] + sPart[3][lane];
        const float x2 = tanhf(a);
        out[2 * B + B * E + b * E + lane] = x2;  // x2_t
        float p = x2 * l3_w[lane];
#pragma unroll
        for (int off = 32; off; off >>= 1) p += __shfl_xor(p, off);
        if (lane == 0) out[B + b] = p + l3_b[0]; // x3_t
    }
}

// ---------------------------------------------------------------------------
extern "C" void kernel_launch(void* const* d_in, const int* in_sizes, int n_in,
                              void* d_out, int out_size, void* d_ws, size_t ws_size,
                              hipStream_t stream) {
    const int*   x            = (const int*)d_in[0];
    const int*   src_his      = (const int*)d_in[1];
    const int*   src_hl       = (const int*)d_in[2];
    const int*   tgt_his      = (const int*)d_in[3];
    const int*   tgt_hl       = (const int*)d_in[4];
    const int*   sample_idx   = (const int*)d_in[5];
    const int*   supp_users   = (const int*)d_in[6];
    const float* src_user_emb = (const float*)d_in[7];
    const float* src_item_emb = (const float*)d_in[8];
    const float* tgt_user_emb = (const float*)d_in[9];
    const float* tgt_item_emb = (const float*)d_in[10];
    const float* W_att_w      = (const float*)d_in[11];
    const float* W_att_b      = (const float*)d_in[12];
    const float* W_agg_w      = (const float*)d_in[13];
    const float* Wq           = (const float*)d_in[14];
    const float* Wk           = (const float*)d_in[15];
    const float* Wv           = (const float*)d_in[16];
    const float* W_out        = (const float*)d_in[17];
    const float* l1_w         = (const float*)d_in[18];
    const float* l1_b         = (const float*)d_in[19];
    const float* l2_w         = (const float*)d_in[20];
    const float* l2_b         = (const float*)d_in[21];
    const float* l3_w         = (const float*)d_in[22];
    const float* l3_b         = (const float*)d_in[23];

    float* ws      = (float*)d_ws;
    float* qarr    = ws;                                  // 2*H*B*E
    float* K_supp  = qarr + 2 * H * B * E;                // H*SUPP*E
    float* garr    = K_supp + H * SUPP * E;               // 2*B*H*E
    float* out     = (float*)d_out;

    pre_kernel<<<dim3(B, 3), 256, 0, stream>>>(
        x, src_his, src_hl, tgt_his, tgt_hl, src_item_emb,
        src_user_emb, tgt_user_emb, supp_users,
        W_att_w, W_att_b, W_agg_w, Wq, Wk, qarr, K_supp);
    attn_kernel<<<dim3(B * H * 2), 256, 0, stream>>>(
        sample_idx, K_supp, qarr, Wv, garr);
    final_kernel<<<dim3(B), 256, 0, stream>>>(
        x, tgt_item_emb, garr, garr + B * H * E, W_out,
        l1_w, l1_b, l2_w, l2_b, l3_w, l3_b, out);
}

// Round 9
// 281.232 us; speedup vs baseline: 1.0592x; 1.0592x over previous
//
#include <hip/hip_runtime.h>

// Problem constants (from reference)
constexpr int B    = 1024;
constexpr int L    = 50;
constexpr int S    = 256;
constexpr int H    = 4;
constexpr int E    = 64;
constexpr int HID  = 64;
constexpr int SUPP = 10000;

// Broadcast lane l's value to all lanes of the wave (l must be wave-uniform;
// compiles to v_readlane -> SGPR, usable as the scalar operand of v_fma).
__device__ __forceinline__ float lanebc(float v, int l) {
    return __int_as_float(__builtin_amdgcn_readlane(__float_as_int(v), l));
}

// 64-long broadcast dot, 2 chains.
__device__ __forceinline__ float bcdot64(float v, const float* w) {
    float a0 = 0.0f, a1 = 0.0f;
#pragma unroll
    for (int i = 0; i < E; i += 2) {
        a0 += lanebc(v, i)     * w[i];
        a1 += lanebc(v, i + 1) * w[i + 1];
    }
    return a0 + a1;
}

// ---------------------------------------------------------------------------
// Kernel 1: fused pre-work.
//   blockIdx.y in {0,1}: user_fea_encode(call=y) -> fea (2,B,E).
//   blockIdx.y == 2:     E_supp[j] = tgt_user_emb[supp_users[j]]  (all blocks)
//                        + blocks 0..3: M[h]=Wq[h]@Wk[h]^T, WkWv[h]=Wk[h]@Wv[h].
// Algebra: logit = (fea@Wq)·(emb@Wk) == (fea@M)·emb ; g = (Σp·emb)@WkWv.
// K_supp (655 MFLOP + 10 MB) is gone entirely.
// Reference quirks preserved: src_item_emb for BOTH encode calls; encoder
// softmax has no max-subtract, padded rows contribute exp(0)=1; denom+1e-12.
// ---------------------------------------------------------------------------
__global__ __launch_bounds__(256) void pre_kernel(
    const int* __restrict__ x,            // (B,2)  [:,0]=user_id
    const int* __restrict__ src_his,      // (B,L)
    const int* __restrict__ src_hl,       // (B,)
    const int* __restrict__ tgt_his,      // (B,L)
    const int* __restrict__ tgt_hl,       // (B,)
    const float* __restrict__ item_emb,   // src_item_emb -- always src!
    const float* __restrict__ src_user_emb,
    const float* __restrict__ tgt_user_emb,
    const int* __restrict__ supp_users,   // (SUPP,)
    const float* __restrict__ W_att_w,    // (E,E)
    const float* __restrict__ W_att_b,    // (E,)
    const float* __restrict__ W_agg_w,    // (E,E)
    const float* __restrict__ Wq,         // (H,E,E)
    const float* __restrict__ Wk,         // (H,E,E)
    const float* __restrict__ Wv,         // (H,E,E)
    float* __restrict__ feaout,           // (2,B,E)
    float* __restrict__ E_supp,           // (SUPP,E)
    float* __restrict__ Mmat,             // (H,E,E)
    float* __restrict__ WkWv)             // (H,E,E)
{
    const int tid  = threadIdx.x;
    const int lane = tid & 63;
    const int wave = tid >> 6;

    if (blockIdx.y == 2) {
        const int bid = blockIdx.x;
        if (bid < H) {
            // ---- M[h][i][j] = sum_o Wq[h][i][o] * Wk[h][j][o], lane = j ----
            const int h = bid;
            float wrow[E];
#pragma unroll
            for (int o = 0; o < E; o++) wrow[o] = Wk[h * E * E + lane * E + o];
#pragma unroll
            for (int k = 0; k < 16; k++) {
                const int i = wave * 16 + k;
                float a0 = 0.0f, a1 = 0.0f;
#pragma unroll
                for (int o = 0; o < E; o += 2) {
                    a0 += Wq[h * E * E + i * E + o]     * wrow[o];     // uniform -> s_load
                    a1 += Wq[h * E * E + i * E + o + 1] * wrow[o + 1];
                }
                Mmat[h * E * E + i * E + lane] = a0 + a1;
            }
            // ---- WkWv[h][i][j] = sum_o Wk[h][i][o] * Wv[h][o][j], lane = j ----
#pragma unroll
            for (int o = 0; o < E; o++) wrow[o] = Wv[h * E * E + o * E + lane];
#pragma unroll
            for (int k = 0; k < 16; k++) {
                const int i = wave * 16 + k;
                float a0 = 0.0f, a1 = 0.0f;
#pragma unroll
                for (int o = 0; o < E; o += 2) {
                    a0 += Wk[h * E * E + i * E + o]     * wrow[o];
                    a1 += Wk[h * E * E + i * E + o + 1] * wrow[o + 1];
                }
                WkWv[h * E * E + i * E + lane] = a0 + a1;
            }
        }
        // ---- E_supp copy (all plane-2 blocks) ----
        for (int j = bid + (wave << 10); j < SUPP; j += 4096) {
            E_supp[(size_t)j * E + lane] =
                tgt_user_emb[(size_t)supp_users[j] * E + lane];
        }
        return;
    }

    // ---------------- encode plane ----------------
    __shared__ float sHist[L * E];
    __shared__ float sAtt[L];
    __shared__ float sPart[4][E];
    __shared__ float sOut[E];

    const int b    = blockIdx.x;
    const int call = blockIdx.y;

    const int* his = call ? tgt_his : src_his;
    const int* hl  = call ? tgt_hl  : src_hl;
    const float* user_table = call ? tgt_user_emb : src_user_emb;

    float wcol[E];
#pragma unroll
    for (int i = 0; i < E; i++) wcol[i] = W_att_w[i * E + lane];

    const int uid    = x[2 * b];
    const float uv   = user_table[(size_t)uid * E + lane];
    const float bias = W_att_b[lane];
    const int hlen   = hl[b];

    // stage ALL history rows (masked) to LDS; synchronous (L1-served reuse)
#pragma unroll
    for (int i = 0; i < 13; i++) {
        const int l = wave + 4 * i;
        if (l < L) {
            const int it = his[b * L + l];
            sHist[l * E + lane] = (l < hlen) ? item_emb[(size_t)it * E + lane] : 0.0f;
        }
    }
    __syncthreads();

    // key-matmul + logits, 4 rows deep (4 independent rl+fmac chains)
#pragma unroll
    for (int g = 0; g < 3; g++) {
        const int l0 = wave + 16 * g;
        const int l1 = l0 + 4, l2 = l0 + 8, l3 = l0 + 12;
        const float h0 = sHist[l0 * E + lane];
        const float h1 = sHist[l1 * E + lane];
        const float h2 = sHist[l2 * E + lane];
        const float h3 = sHist[l3 * E + lane];
        float a0 = bias, a1 = bias, a2 = bias, a3 = bias;
#pragma unroll
        for (int i = 0; i < E; i++) {
            a0 += lanebc(h0, i) * wcol[i];
            a1 += lanebc(h1, i) * wcol[i];
            a2 += lanebc(h2, i) * wcol[i];
            a3 += lanebc(h3, i) * wcol[i];
        }
        float p0 = tanhf(a0) * uv, p1 = tanhf(a1) * uv;
        float p2 = tanhf(a2) * uv, p3 = tanhf(a3) * uv;
        float s0 = h0, s1 = h1, s2 = h2, s3 = h3;
#pragma unroll
        for (int off = 32; off; off >>= 1) {
            p0 += __shfl_xor(p0, off); s0 += __shfl_xor(s0, off);
            p1 += __shfl_xor(p1, off); s1 += __shfl_xor(s1, off);
            p2 += __shfl_xor(p2, off); s2 += __shfl_xor(s2, off);
            p3 += __shfl_xor(p3, off); s3 += __shfl_xor(s3, off);
        }
        if (lane == 0) {
            sAtt[l0] = (s0 == 0.0f) ? 0.0f : p0;
            sAtt[l1] = (s1 == 0.0f) ? 0.0f : p1;
            sAtt[l2] = (s2 == 0.0f) ? 0.0f : p2;
            sAtt[l3] = (s3 == 0.0f) ? 0.0f : p3;
        }
    }
    {   // leftover row l = wave + 48 (waves 0,1 only)
        const int l = wave + 48;
        if (l < L) {
            const float hv = sHist[l * E + lane];
            const float a = bias + bcdot64(hv, wcol);
            float part = tanhf(a) * uv;
            float hsum = hv;
#pragma unroll
            for (int off = 32; off; off >>= 1) {
                part += __shfl_xor(part, off);
                hsum += __shfl_xor(hsum, off);
            }
            if (lane == 0) sAtt[l] = (hsum == 0.0f) ? 0.0f : part;
        }
    }
    __syncthreads();

    // softmax (no max-subtract; padded rows contribute exp(0)=1)
    if (wave == 0) {
        float v = (lane < L) ? expf(sAtt[lane]) : 0.0f;
        float s = v;
#pragma unroll
        for (int off = 32; off; off >>= 1) s += __shfl_xor(s, off);
        const float denom = s + 1e-12f;
        if (lane < L) sAtt[lane] = v / denom;
    }
    __syncthreads();

    // ctx partials across waves (2 accumulators)
    {
        float c0 = 0.0f, c1 = 0.0f;
        for (int l = wave; l < L; l += 8) c0 += sAtt[l] * sHist[l * E + lane];
        for (int l = wave + 4; l < L; l += 8) c1 += sAtt[l] * sHist[l * E + lane];
        sPart[wave][lane] = c0 + c1;
    }
    __syncthreads();
    if (tid < E) sOut[tid] = sPart[0][tid] + sPart[1][tid] + sPart[2][tid] + sPart[3][tid];
    __syncthreads();

    // agg: fea = ctx @ W_agg, i-range split across waves (2 accumulators)
    {
        float g0 = 0.0f, g1 = 0.0f;
#pragma unroll
        for (int k = 0; k < 16; k += 2) {
            const int i = wave * 16 + k;
            g0 += sOut[i]     * W_agg_w[i * E + lane];
            g1 += sOut[i + 1] * W_agg_w[(i + 1) * E + lane];
        }
        sPart[wave][lane] = g0 + g1;
    }
    __syncthreads();

    if (wave == 0) {
        feaout[((size_t)call * B + b) * E + lane] =
            sPart[0][lane] + sPart[1][lane] + sPart[2][lane] + sPart[3][lane];
    }
}

// ---------------------------------------------------------------------------
// Kernel 2: attention per (b,h,call), flat grid (h = bid&3).  Gathers RAW
// support embeddings from the 2.56 MB E_supp table (head-shared -> fully
// L2-resident on every XCD).  qm = fea@M[h] computed by wave 0 into LDS.
// logit_s = qm · emb_s ; softmax (max-subtracted) ; ctx = Σ p_s emb_s ;
// g = ctx @ WkWv[h].  Mathematically identical to the reference chain.
// ---------------------------------------------------------------------------
__global__ __launch_bounds__(256) void attn_kernel(
    const int* __restrict__ sample_idx,  // (2,H,B,S)
    const float* __restrict__ E_supp,    // (SUPP,E)
    const float* __restrict__ fea,       // (2,B,E)
    const float* __restrict__ Mmat,      // (H,E,E)
    const float* __restrict__ WkWv,      // (H,E,E)
    float* __restrict__ gout)            // (2,B,H*E)
{
    __shared__ float sQ[E];
    __shared__ float sRed[8];
    __shared__ float sCtx[4][E];
    __shared__ float sC[E];
    __shared__ float sG[4][E];

    const int bid  = blockIdx.x;
    const int h    = bid & 3;
    const int call = (bid >> 2) & 1;
    const int b    = bid >> 3;
    const int tid  = threadIdx.x;
    const int lane = tid & 63;
    const int wave = tid >> 6;
    const int u    = lane & 15;
    const int rsub = lane >> 4;
    const int s0   = wave * 64;

    // ---- qm = fea @ M[h]  (wave 0; lane = output col) ----
    if (wave == 0) {
        const float feav = fea[((size_t)call * B + b) * E + lane];
        const float* Mh = Mmat + h * E * E;
        float a0 = 0.0f, a1 = 0.0f;
#pragma unroll
        for (int i = 0; i < E; i += 2) {
            a0 += lanebc(feav, i)     * Mh[i * E + lane];
            a1 += lanebc(feav, i + 1) * Mh[(i + 1) * E + lane];
        }
        sQ[lane] = a0 + a1;
    }
    __syncthreads();

    const int* idx = sample_idx + (((call * H) + h) * B + b) * S;
    const float4 qu = *(const float4*)(sQ + 4 * u);

    // ---- gather raw emb rows into registers + logits ----
    float4 kreg[16];
    float mylogit = 0.0f;
#pragma unroll
    for (int i = 0; i < 16; i++) {
        const int j = idx[s0 + 4 * i + rsub];
        kreg[i] = *(const float4*)(E_supp + (size_t)j * E + 4 * u);
        float part = kreg[i].x * qu.x + kreg[i].y * qu.y
                   + kreg[i].z * qu.z + kreg[i].w * qu.w;
#pragma unroll
        for (int off = 1; off < 16; off <<= 1) part += __shfl_xor(part, off);
        mylogit = (u == i) ? part : mylogit;   // lane holds row s0 + 4u + rsub
    }

    // ---- block softmax over 256 logits (permutation-invariant) ----
    float m = mylogit;
#pragma unroll
    for (int off = 32; off; off >>= 1) m = fmaxf(m, __shfl_xor(m, off));
    if (lane == 0) sRed[wave] = m;
    __syncthreads();
    const float mx = fmaxf(fmaxf(sRed[0], sRed[1]), fmaxf(sRed[2], sRed[3]));
    const float ex = expf(mylogit - mx);
    float sm = ex;
#pragma unroll
    for (int off = 32; off; off >>= 1) sm += __shfl_xor(sm, off);
    if (lane == 0) sRed[4 + wave] = sm;
    __syncthreads();
    const float denom = sRed[4] + sRed[5] + sRed[6] + sRed[7];
    const float pval = ex / denom;   // weight of row s0 + 4u + rsub

    // ---- ctx_raw: pure-VALU FMA over register tile ----
    float4 cacc = make_float4(0.0f, 0.0f, 0.0f, 0.0f);
#pragma unroll
    for (int i = 0; i < 16; i++) {
        const float p = __shfl(pval, (lane & 48) + i);
        cacc.x += p * kreg[i].x;
        cacc.y += p * kreg[i].y;
        cacc.z += p * kreg[i].z;
        cacc.w += p * kreg[i].w;
    }
#pragma unroll
    for (int off = 16; off <= 32; off <<= 1) {
        cacc.x += __shfl_xor(cacc.x, off);
        cacc.y += __shfl_xor(cacc.y, off);
        cacc.z += __shfl_xor(cacc.z, off);
        cacc.w += __shfl_xor(cacc.w, off);
    }
    if (lane < 16) *(float4*)(&sCtx[wave][u * 4]) = cacc;
    __syncthreads();
    if (wave == 0) {
        sC[lane] = sCtx[0][lane] + sCtx[1][lane] + sCtx[2][lane] + sCtx[3][lane];
    }
    __syncthreads();

    // ---- g = ctx_raw @ WkWv[h], c-range split across waves ----
    const float* Wh = WkWv + h * E * E;
    float g0 = 0.0f, g1 = 0.0f;
#pragma unroll
    for (int k = 0; k < 16; k += 2) {
        const int c = wave * 16 + k;
        g0 += sC[c]     * Wh[c * E + lane];
        g1 += sC[c + 1] * Wh[(c + 1) * E + lane];
    }
    sG[wave][lane] = g0 + g1;
    __syncthreads();
    if (wave == 0) {
        gout[((size_t)(call * B) + b) * (H * E) + h * E + lane] =
            sG[0][lane] + sG[1][lane] + sG[2][lane] + sG[3][lane];
    }
}

// ---------------------------------------------------------------------------
// Kernel 3: W_out projection + final MLP + all four outputs.
// out layout: [output(B) | x3(B) | out_emb_s(B*E) | x2(B*E)]
// ---------------------------------------------------------------------------
__global__ __launch_bounds__(256) void final_kernel(
    const int* __restrict__ x,             // (B,2) [:,1]=item_id
    const float* __restrict__ tgt_item_emb,
    const float* __restrict__ gsrc,        // (B, H*E) -> user_emb path
    const float* __restrict__ gtgt,        // (B, H*E) -> hybrid path
    const float* __restrict__ W_out,       // (H*E, E)
    const float* __restrict__ l1_w,        // (2E, HID)
    const float* __restrict__ l1_b,        // (HID,)
    const float* __restrict__ l2_w,        // (HID, E)
    const float* __restrict__ l2_b,        // (E,)
    const float* __restrict__ l3_w,        // (E,1)
    const float* __restrict__ l3_b,        // (1,)
    float* __restrict__ out)
{
    __shared__ float sPart[4][E];
    __shared__ float sHyb[E];
    __shared__ float sItem[E];
    __shared__ float sX1[HID];

    const int b    = blockIdx.x;
    const int tid  = threadIdx.x;
    const int lane = tid & 63;
    const int wave = tid >> 6;

    if (tid < E) {
        const int item = x[2 * b + 1];
        sItem[tid] = tgt_item_emb[(size_t)item * E + tid];
    }

    const float* grow = (wave < 2) ? (gsrc + (size_t)b * (H * E))
                                   : (gtgt + (size_t)b * (H * E));
    const int i0 = (wave & 1) * 128;
    float a0 = 0.0f, a1 = 0.0f, a2 = 0.0f, a3 = 0.0f;
    for (int i = i0; i < i0 + 128; i += 4) {
        a0 += grow[i]     * W_out[i * E + lane];
        a1 += grow[i + 1] * W_out[(i + 1) * E + lane];
        a2 += grow[i + 2] * W_out[(i + 2) * E + lane];
        a3 += grow[i + 3] * W_out[(i + 3) * E + lane];
    }
    sPart[wave][lane] = (a0 + a1) + (a2 + a3);
    __syncthreads();

    if (wave == 0) {
        const float ue = sPart[0][lane] + sPart[1][lane];
        const float prod = ue * sItem[lane];
        out[2 * B + b * E + lane] = prod;  // out_emb_s
        float s = prod;
#pragma unroll
        for (int off = 32; off; off >>= 1) s += __shfl_xor(s, off);
        if (lane == 0) out[b] = s;         // output
    }
    if (wave == 1) {
        sHyb[lane] = sPart[2][lane] + sPart[3][lane];
    }
    __syncthreads();

    // l1: 128-deep sum split across 4 waves, 4 accumulators
    {
        float b0 = 0.0f, b1 = 0.0f, b2 = 0.0f, b3 = 0.0f;
#pragma unroll
        for (int k = 0; k < 32; k += 4) {
            const int i = wave * 32 + k;
            const float v0 = (i < 64)     ? sHyb[i]     : sItem[i - 64];
            const float v1 = (i + 1 < 64) ? sHyb[i + 1] : sItem[i + 1 - 64];
            const float v2 = (i + 2 < 64) ? sHyb[i + 2] : sItem[i + 2 - 64];
            const float v3 = (i + 3 < 64) ? sHyb[i + 3] : sItem[i + 3 - 64];
            b0 += v0 * l1_w[i * HID + lane];
            b1 += v1 * l1_w[(i + 1) * HID + lane];
            b2 += v2 * l1_w[(i + 2) * HID + lane];
            b3 += v3 * l1_w[(i + 3) * HID + lane];
        }
        sPart[wave][lane] = (b0 + b1) + (b2 + b3);
    }
    __syncthreads();

    if (wave == 0) {
        const float a = l1_b[lane] + sPart[0][lane] + sPart[1][lane]
                      + sPart[2][lane] + sPart[3][lane];
        sX1[lane] = tanhf(a);
    }
    __syncthreads();

    // l2: 64-deep sum split across 4 waves (16 each), 4 accumulators
    {
        float c0 = 0.0f, c1 = 0.0f, c2 = 0.0f, c3 = 0.0f;
#pragma unroll
        for (int k = 0; k < 16; k += 4) {
            const int i = wave * 16 + k;
            c0 += sX1[i]     * l2_w[i * E + lane];
            c1 += sX1[i + 1] * l2_w[(i + 1) * E + lane];
            c2 += sX1[i + 2] * l2_w[(i + 2) * E + lane];
            c3 += sX1[i + 3] * l2_w[(i + 3) * E + lane];
        }
        sPart[wave][lane] = (c0 + c1) + (c2 + c3);
    }
    __syncthreads();

    if (wave == 0) {
        const float a = l2_b[lane] + sPart[0][lane] + sPart[1][lane]
                      + sPart[2][lane] + sPart[3][lane];
        const float x2 = tanhf(a);
        out[2 * B + B * E + b * E + lane] = x2;  // x2_t
        float p = x2 * l3_w[lane];
#pragma unroll
        for (int off = 32; off; off >>= 1) p += __shfl_xor(p, off);
        if (lane == 0) out[B + b] = p + l3_b[0]; // x3_t
    }
}

// ---------------------------------------------------------------------------
extern "C" void kernel_launch(void* const* d_in, const int* in_sizes, int n_in,
                              void* d_out, int out_size, void* d_ws, size_t ws_size,
                              hipStream_t stream) {
    const int*   x            = (const int*)d_in[0];
    const int*   src_his      = (const int*)d_in[1];
    const int*   src_hl       = (const int*)d_in[2];
    const int*   tgt_his      = (const int*)d_in[3];
    const int*   tgt_hl       = (const int*)d_in[4];
    const int*   sample_idx   = (const int*)d_in[5];
    const int*   supp_users   = (const int*)d_in[6];
    const float* src_user_emb = (const float*)d_in[7];
    const float* src_item_emb = (const float*)d_in[8];
    const float* tgt_user_emb = (const float*)d_in[9];
    const float* tgt_item_emb = (const float*)d_in[10];
    const float* W_att_w      = (const float*)d_in[11];
    const float* W_att_b      = (const float*)d_in[12];
    const float* W_agg_w      = (const float*)d_in[13];
    const float* Wq           = (const float*)d_in[14];
    const float* Wk           = (const float*)d_in[15];
    const float* Wv           = (const float*)d_in[16];
    const float* W_out        = (const float*)d_in[17];
    const float* l1_w         = (const float*)d_in[18];
    const float* l1_b         = (const float*)d_in[19];
    const float* l2_w         = (const float*)d_in[20];
    const float* l2_b         = (const float*)d_in[21];
    const float* l3_w         = (const float*)d_in[22];
    const float* l3_b         = (const float*)d_in[23];

    float* ws      = (float*)d_ws;
    float* fea     = ws;                                  // 2*B*E
    float* E_supp  = fea + 2 * B * E;                     // SUPP*E
    float* Mmat    = E_supp + SUPP * E;                   // H*E*E
    float* WkWv    = Mmat + H * E * E;                    // H*E*E
    float* garr    = WkWv + H * E * E;                    // 2*B*H*E
    float* out     = (float*)d_out;

    pre_kernel<<<dim3(B, 3), 256, 0, stream>>>(
        x, src_his, src_hl, tgt_his, tgt_hl, src_item_emb,
        src_user_emb, tgt_user_emb, supp_users,
        W_att_w, W_att_b, W_agg_w, Wq, Wk, Wv,
        fea, E_supp, Mmat, WkWv);
    attn_kernel<<<dim3(B * H * 2), 256, 0, stream>>>(
        sample_idx, E_supp, fea, Mmat, WkWv, garr);
    final_kernel<<<dim3(B), 256, 0, stream>>>(
        x, tgt_item_emb, garr, garr + B * H * E, W_out,
        l1_w, l1_b, l2_w, l2_b, l3_w, l3_b, out);
}